// Round 1
// baseline (186.894 us; speedup 1.0000x reference)
//
#include <hip/hip_runtime.h>

#define LRC   0.01f
#define WCLIP 5.0f
#define LO   (-4.5951198501345898f)
#define HI   ( 4.5951198501345898f)

__device__ __forceinline__ unsigned short f2bf(float f) {
    unsigned int u = __float_as_uint(f);
    u += 0x7fffu + ((u >> 16) & 1u);          // RNE
    return (unsigned short)(u >> 16);
}
__device__ __forceinline__ float bflo(unsigned int p) { return __uint_as_float(p << 16); }
__device__ __forceinline__ float bfhi(unsigned int p) { return __uint_as_float(p & 0xffff0000u); }

// ---------------------------------------------------------------------------
// K1: distances GEMM (4096x512 @ 512x256) -> idx. LDS-tiled. 64x64 tile,
//     4x4/thread, BK=64, register-prefetch of next tile overlaps HBM with the
//     64-step FMA loop. Ascending-k fp32 fmaf chain == R0 bitwise.
//     Blocks 256..319: transpose logits (1024x256) -> lT (256x1024).
//     (unchanged this round — attribution: all delta belongs to k2)
// ---------------------------------------------------------------------------
__global__ __launch_bounds__(256) void k1_idx_lt(
    const float* __restrict__ cmap,    // (4096, 512)
    const float* __restrict__ ctx,     // (512, 256)
    const float* __restrict__ cbias,   // (4096)
    const float* __restrict__ logits,  // (1024, 256)
    int*   __restrict__ idxb,          // (1024, 256)
    float* __restrict__ lT)            // (256, 1024)
{
    __shared__ __align__(16) float As[64 * 68];   // As[k][m], stride 68
    __shared__ __align__(16) float Bs[64 * 68];   // Bs[k][n], stride 68
    const int t   = threadIdx.x;
    const int blk = blockIdx.x;

    if (blk < 256) {
        const int gm = blk >> 2, gn = blk & 3;
        const int m0 = gm << 6, n0 = gn << 6;
        const int tm = t >> 4, tn = t & 15;

        const int rs = t >> 4;             // row step base
        const int cs = (t & 15) << 2;      // fixed 4-col offset

        float acc[4][4];
        #pragma unroll
        for (int i = 0; i < 4; i++)
            #pragma unroll
            for (int j = 0; j < 4; j++) acc[i][j] = 0.f;

        float4 va[4], vb[4];
        #pragma unroll
        for (int rep = 0; rep < 4; rep++) {
            va[rep] = *(const float4*)(cmap + (m0 + (rep << 4) + rs) * 512 + cs);
            vb[rep] = *(const float4*)(ctx + (((rep << 4) + rs)) * 256 + n0 + cs);
        }

        for (int k0 = 0; k0 < 512; k0 += 64) {
            __syncthreads();
            #pragma unroll
            for (int rep = 0; rep < 4; rep++) {
                const int r = (rep << 4) + rs;
                As[(cs + 0) * 68 + r] = va[rep].x;
                As[(cs + 1) * 68 + r] = va[rep].y;
                As[(cs + 2) * 68 + r] = va[rep].z;
                As[(cs + 3) * 68 + r] = va[rep].w;
                *(float4*)(Bs + r * 68 + cs) = vb[rep];
            }
            if (k0 + 64 < 512) {
                #pragma unroll
                for (int rep = 0; rep < 4; rep++) {
                    va[rep] = *(const float4*)(cmap + (m0 + (rep << 4) + rs) * 512 + k0 + 64 + cs);
                    vb[rep] = *(const float4*)(ctx + (k0 + 64 + (rep << 4) + rs) * 256 + n0 + cs);
                }
            }
            __syncthreads();

            const float* ap = As + (tm << 2);
            const float* bp = Bs + (tn << 2);
            #pragma unroll 8
            for (int k = 0; k < 64; ++k) {
                float4 a4 = *(const float4*)(ap + k * 68);
                float4 b4 = *(const float4*)(bp + k * 68);
                acc[0][0] = fmaf(a4.x, b4.x, acc[0][0]);
                acc[0][1] = fmaf(a4.x, b4.y, acc[0][1]);
                acc[0][2] = fmaf(a4.x, b4.z, acc[0][2]);
                acc[0][3] = fmaf(a4.x, b4.w, acc[0][3]);
                acc[1][0] = fmaf(a4.y, b4.x, acc[1][0]);
                acc[1][1] = fmaf(a4.y, b4.y, acc[1][1]);
                acc[1][2] = fmaf(a4.y, b4.z, acc[1][2]);
                acc[1][3] = fmaf(a4.y, b4.w, acc[1][3]);
                acc[2][0] = fmaf(a4.z, b4.x, acc[2][0]);
                acc[2][1] = fmaf(a4.z, b4.y, acc[2][1]);
                acc[2][2] = fmaf(a4.z, b4.z, acc[2][2]);
                acc[2][3] = fmaf(a4.z, b4.w, acc[2][3]);
                acc[3][0] = fmaf(a4.w, b4.x, acc[3][0]);
                acc[3][1] = fmaf(a4.w, b4.y, acc[3][1]);
                acc[3][2] = fmaf(a4.w, b4.z, acc[3][2]);
                acc[3][3] = fmaf(a4.w, b4.w, acc[3][3]);
            }
        }
        const int s = (gm << 4) + tm;
        int4 iv;
        int* ivp = &iv.x;
        float cb[4];
        #pragma unroll
        for (int i = 0; i < 4; i++) cb[i] = cbias[(s << 2) + i];
        #pragma unroll
        for (int j = 0; j < 4; j++) {
            int v = 0;
            #pragma unroll
            for (int i = 0; i < 4; i++)
                v |= (acc[i][j] > cb[i]) ? (1 << i) : 0;
            ivp[j] = v;
        }
        *(int4*)(idxb + s * 256 + n0 + (tn << 2)) = iv;
    } else {
        float* T = As;
        const int bi = blk - 256;
        const int i0 = (bi >> 2) << 6;
        const int b0 = (bi & 3) << 6;
        #pragma unroll
        for (int rep = 0; rep < 4; rep++) {
            int flat4 = rep * 256 + t;
            int r = flat4 >> 4;
            int c = (flat4 & 15) << 2;
            float4 v = *(const float4*)(logits + (i0 + r) * 256 + b0 + c);
            T[(c + 0) * 68 + r] = v.x;
            T[(c + 1) * 68 + r] = v.y;
            T[(c + 2) * 68 + r] = v.z;
            T[(c + 3) * 68 + r] = v.w;
        }
        __syncthreads();
        #pragma unroll
        for (int rep = 0; rep < 4; rep++) {
            int flat4 = rep * 256 + t;
            int r = flat4 >> 4;
            int c = (flat4 & 15) << 2;
            *(float4*)(lT + (b0 + r) * 1024 + i0 + c) =
                *(const float4*)(T + r * 68 + c);
        }
    }
}

// ---------------------------------------------------------------------------
// K2 (rewritten): 512 blocks x 1024 thr, 2 neurons/block.
//   - Whole 32x1024 weight block staged ONCE to LDS as packed bf16 (exact for
//     the 2^-10 input weights) -> 2 barriers total instead of 32.
//   - LDS row stride 514 dwords: gather of <=16 distinct rows at a common col
//     maps to banks (2j+c)%32, all distinct -> conflict-free ds_read_b64.
//   - ~72.5 KB LDS + VGPR<=64 (__launch_bounds__(1024,8)) -> 2 blocks/CU,
//     32 waves/CU; independent blocks cover each other's barrier drains.
//   - Epilogue reads original weights back from LDS (bf16-exact) -> the 64 MB
//     global re-read is gone; epilogue is write-bound only.
//   - Per-(g,b,q) FMA chain keeps the exact i-order of the previous kernel
//     (c0 stripes, 4-quarter split, q1+q2+q3 reduce order) -> outp/outw
//     bitwise identical to the passing version.
// ---------------------------------------------------------------------------
#define WSTRIDE 514   // dwords per LDS weight row (512 data + 2 pad)

__global__ __launch_bounds__(1024, 8) void k2_fwd_upd(
    const float* __restrict__ logits,   // (1024, 256)
    const float* __restrict__ targets,  // (256)
    const float* __restrict__ weights,  // (1024, 16, 1024)
    const float* __restrict__ bias,     // (1)
    const int*   __restrict__ idxb,     // (1024, 256)
    const float* __restrict__ lT,       // (256, 1024)
    float* __restrict__ outp,           // d_out first 1024*256
    float* __restrict__ outw)           // d_out + 1024*256
{
    __shared__ __align__(16) unsigned int wlds[32 * WSTRIDE];  // 65792 B packed bf16
    __shared__ float red[3 * 2 * 256];                         // q=1..3 partials
    __shared__ float sig_lds[2 * 256];
    __shared__ int   lastb[32];
    __shared__ float cf_lds[32];

    const int t  = threadIdx.x;
    const int b  = t & 255;
    const int q  = t >> 8;               // i-quarter 0..3
    const int s0 = blockIdx.x << 1;      // 2 neurons/block

    if (t < 32) lastb[t] = -1;

    int jg[2], rowoff[2];
    #pragma unroll
    for (int g = 0; g < 2; g++) {
        jg[g] = idxb[(s0 + g) * 256 + b];
        rowoff[g] = ((g << 4) + jg[g]) * WSTRIDE;
    }

    // ---- stage all 32 rows x 1024 cols as bf16 pairs (single pass) ----
    // 8192 float4 / 1024 thr = 8 per thread; coalesced float4 reads.
    #pragma unroll
    for (int seg = 0; seg < 8; ++seg) {
        const int flat4 = (seg << 10) + t;
        const int r  = flat4 >> 8;              // 0..31 = g*16 + j
        const int c4 = (flat4 & 255) << 2;      // col 0..1020
        float4 v = *(const float4*)(weights +
                      ((size_t)(s0 + (r >> 4)) << 14) + ((r & 15) << 10) + c4);
        unsigned int p0 = (unsigned int)f2bf(v.x) | ((unsigned int)f2bf(v.y) << 16);
        unsigned int p1 = (unsigned int)f2bf(v.z) | ((unsigned int)f2bf(v.w) << 16);
        *(uint2*)(wlds + r * WSTRIDE + (c4 >> 1)) = make_uint2(p0, p1);
    }
    __syncthreads();

    // ---- dot: same i-order as before (c0 stripes, quarter qq) ----
    float acc[2] = {0.f, 0.f};
    const int qq = q << 4;
    for (int c0 = 0; c0 < 16; ++c0) {
        const int ibase = (c0 << 6) + qq;
        #pragma unroll
        for (int ii = 0; ii < 16; ii += 4) {
            const int i = ibase + ii;
            float l0 = logits[(i + 0) * 256 + b];
            float l1 = logits[(i + 1) * 256 + b];
            float l2 = logits[(i + 2) * 256 + b];
            float l3 = logits[(i + 3) * 256 + b];
            #pragma unroll
            for (int g = 0; g < 2; g++) {
                uint2 wp = *(const uint2*)(wlds + rowoff[g] + (i >> 1));
                acc[g] = fmaf(bflo(wp.x), l0, acc[g]);
                acc[g] = fmaf(bfhi(wp.x), l1, acc[g]);
                acc[g] = fmaf(bflo(wp.y), l2, acc[g]);
                acc[g] = fmaf(bfhi(wp.y), l3, acc[g]);
            }
        }
    }

    // ---- reduce i-quarters (same order: acc + q1 + q2 + q3) ----
    if (q > 0) {
        #pragma unroll
        for (int g = 0; g < 2; g++) red[((q - 1) * 2 + g) * 256 + b] = acc[g];
    }
    __syncthreads();
    if (q == 0) {
        #pragma unroll
        for (int g = 0; g < 2; g++) {
            float tot = acc[g] + red[(0 * 2 + g) * 256 + b]
                               + red[(1 * 2 + g) * 256 + b]
                               + red[(2 * 2 + g) * 256 + b];
            float outv = fminf(fmaxf(tot, LO), HI);
            if (s0 + g == 0) outv = bias[0];      // neuron 0 forced to bias
            outp[(s0 + g) * 256 + b] = outv;
            sig_lds[(g << 8) + b] = 1.f / (1.f + __expf(-outv));
            atomicMax(&lastb[(g << 4) + jg[g]], b);
        }
    }
    __syncthreads();
    if (t < 32) {
        int g  = t >> 4;
        int bb = lastb[t];
        float cfv = 0.f;
        if (bb >= 0) cfv = LRC * (sig_lds[(g << 8) + bb] - targets[bb]);
        cf_lds[t] = cfv;
    }
    __syncthreads();

    // ---- fused update epilogue: weights from LDS (bf16-exact), write-only ----
    const int er = t >> 5;               // row 0..31 = g*16 + j
    const int ec = (t & 31) << 2;        // col base 0..124
    const size_t rowbase = ((size_t)(s0 + (er >> 4)) << 14) + ((size_t)(er & 15) << 10);
    const int   col = lastb[er];         // uniform within 32-lane row group
    const float cf  = cf_lds[er];
    const float* lrow = lT + ((size_t)(col < 0 ? 0 : col) << 10);
    const unsigned int* wrow = wlds + er * WSTRIDE;
    #pragma unroll 4
    for (int seg = 0; seg < 8; ++seg) {
        const int c2 = ec + (seg << 7);
        uint2 wp = *(const uint2*)(wrow + (c2 >> 1));
        float4 res = make_float4(bflo(wp.x), bfhi(wp.x), bflo(wp.y), bfhi(wp.y));
        if (col >= 0) {
            float4 lv = *(const float4*)(lrow + c2);
            res.x = fminf(fmaxf(res.x - cf * lv.x, -WCLIP), WCLIP);
            res.y = fminf(fmaxf(res.y - cf * lv.y, -WCLIP), WCLIP);
            res.z = fminf(fmaxf(res.z - cf * lv.z, -WCLIP), WCLIP);
            res.w = fminf(fmaxf(res.w - cf * lv.w, -WCLIP), WCLIP);
        }
        *(float4*)(outw + rowbase + c2) = res;
    }
}

// ---------------------------------------------------------------------------
extern "C" void kernel_launch(void* const* d_in, const int* in_sizes, int n_in,
                              void* d_out, int out_size, void* d_ws, size_t ws_size,
                              hipStream_t stream) {
    const float* logits  = (const float*)d_in[0];   // (1024, 256)
    const float* ctx     = (const float*)d_in[1];   // (512, 256)
    const float* targets = (const float*)d_in[2];   // (256)
    const float* weights = (const float*)d_in[3];   // (1024, 16, 1024)
    const float* cmap    = (const float*)d_in[4];   // (1024, 4, 512)
    const float* cbias   = (const float*)d_in[5];   // (1024, 4, 1)
    const float* bias    = (const float*)d_in[6];   // (1)

    float* outp = (float*)d_out;                    // (1024, 256)
    float* outw = outp + 1024 * 256;                // (1024, 16, 1024)

    char* ws = (char*)d_ws;
    int*   idxb = (int*)ws;                         // 1 MB
    float* lT   = (float*)(ws + (1 << 20));         // 1 MB

    k1_idx_lt <<<320, 256, 0, stream>>>(cmap, ctx, cbias, logits, idxb, lT);
    k2_fwd_upd<<<512, 1024, 0, stream>>>(logits, targets, weights, bias, idxb,
                                         lT, outp, outw);
}